// Round 9
// baseline (219.718 us; speedup 1.0000x reference)
//
#include <hip/hip_runtime.h>
#include <stdint.h>

// Problem constants (fixed by the reference)
#define NN 2048      // nodes
#define DE 16        // embedding dim
#define BB 64        // batch
#define CC 64        // in channels
#define OO 64        // out channels
#define BC 4096      // BB*CC
#define KR 192       // K*CC = 3*64 reduction length
#define JJ 12288     // KR*OO

using bf16x8 = __attribute__((ext_vector_type(8))) __bf16;
using f32x4  = __attribute__((ext_vector_type(4))) float;

__device__ __forceinline__ unsigned short f2bf(float f) {
  union { float f; unsigned int u; } v; v.f = f;
  unsigned int u = v.u;
  return (unsigned short)((u + 0x7FFFu + ((u >> 16) & 1u)) >> 16);  // RNE
}
// async global->LDS, 16B per lane. LDS dst is wave-uniform base + lane*16.
__device__ __forceinline__ void gll16(const void* g, void* l) {
  __builtin_amdgcn_global_load_lds(
      (const __attribute__((address_space(1))) unsigned int*)g,
      (__attribute__((address_space(3))) unsigned int*)l, 16, 0, 0);
}

// ---------------------------------------------------------------------------
// Kernel 1 ("prep"):
//   blocks [0,2048):    pack feat [B,N,C] fp32 -> Fbf [N][B*C] bf16 + FbfT [B*C][N]
//   blocks [2048,2560): adjacency softmax(relu(E E^T)), 4 rows per block; Bias; Ebf
//   blocks [2560,2584): permute wp fp32 -> wpT2[j][16] bf16, j = rq*512+o*8+rl,
//     with the ALGEBRAIC FOLD  W0' = W0 - W2,  W2' = 2*W2  so that downstream
//     out = F*W0' + G1*W1 + H*W2'  (H = A@G1) == reference F*W0+G1*W1+G2*W2.
//     This lets gemm2 store H directly (no F re-read / no 2x-F epilogue math).
__global__ __launch_bounds__(256) void prep(const float* __restrict__ feat,
                                            const float* __restrict__ E,
                                            const float* __restrict__ wp,
                                            const float* __restrict__ bp,
                                            unsigned short* __restrict__ Fbf,
                                            unsigned short* __restrict__ FbfT,
                                            unsigned short* __restrict__ Abf,
                                            float* __restrict__ Bias,
                                            unsigned short* __restrict__ Ebf,
                                            unsigned short* __restrict__ wpT2) {
  __shared__ float smem[64 * 65];  // 16.6 KB, reused per branch
  const int id = blockIdx.x;
  const int t  = threadIdx.x;

  if (id < 2048) {
    // ---- pack_feat: b = id>>5, n-tile = (id&31)*64 ----
    float (*tile)[65] = (float (*)[65])smem;  // +1 pad: conflict-free column reads
    const int b  = id >> 5;
    const int n0 = (id & 31) * 64;
    const int tr = t >> 4, tc4 = (t & 15) * 4;
#pragma unroll
    for (int i = 0; i < 4; ++i) {
      const int r = tr + i * 16;
      const float4 v = *(const float4*)(feat + (size_t)b * (NN * CC) + (size_t)(n0 + r) * CC + tc4);
      tile[r][tc4 + 0] = v.x; tile[r][tc4 + 1] = v.y;
      tile[r][tc4 + 2] = v.z; tile[r][tc4 + 3] = v.w;
    }
    __syncthreads();
#pragma unroll
    for (int i = 0; i < 4; ++i) {
      const int r = tr + i * 16;
      const unsigned int lo = f2bf(tile[r][tc4 + 0]) | ((unsigned int)f2bf(tile[r][tc4 + 1]) << 16);
      const unsigned int hi = f2bf(tile[r][tc4 + 2]) | ((unsigned int)f2bf(tile[r][tc4 + 3]) << 16);
      *(uint2*)(Fbf + (size_t)(n0 + r) * BC + b * CC + tc4) = make_uint2(lo, hi);
    }
    // transposed store, 8B per lane (4 consecutive n)
#pragma unroll
    for (int u = 0; u < 4; ++u) {
      const int p = t + u * 256;
      const int c = p >> 4, n4 = (p & 15) * 4;
      const unsigned int lo = f2bf(tile[n4 + 0][c]) | ((unsigned int)f2bf(tile[n4 + 1][c]) << 16);
      const unsigned int hi = f2bf(tile[n4 + 2][c]) | ((unsigned int)f2bf(tile[n4 + 3][c]) << 16);
      *(uint2*)(FbfT + (size_t)(b * CC + c) * NN + n0 + n4) = make_uint2(lo, hi);
    }
  } else if (id < 2560) {
    // ---- adj_softmax, 4 rows per block (correctness verified R6-R8) ----
    const int n0base = (id - 2048) * 4;
    float* esm  = smem;        // [64]
    float* redm = smem + 64;   // [16]
    float* reds = smem + 80;   // [16]
    if (t < 64) esm[t] = E[n0base * 16 + t];
    __syncthreads();
    if (t < 64) Ebf[n0base * 16 + t] = f2bf(esm[t]);
    float er[4][16];
#pragma unroll
    for (int rr = 0; rr < 4; ++rr)
#pragma unroll
      for (int d = 0; d < 16; ++d) er[rr][d] = esm[rr * 16 + d];

    float v[8][4];
    float mx[4] = {0.f, 0.f, 0.f, 0.f};  // relu floor
#pragma unroll
    for (int i = 0; i < 8; ++i) {
      const int m = t + i * 256;
      const float4* Em = (const float4*)(E + m * 16);
      const float4 a = Em[0], b = Em[1], c = Em[2], d = Em[3];
#pragma unroll
      for (int rr = 0; rr < 4; ++rr) {
        float dot = er[rr][0] * a.x + er[rr][1] * a.y + er[rr][2] * a.z + er[rr][3] * a.w
                  + er[rr][4] * b.x + er[rr][5] * b.y + er[rr][6] * b.z + er[rr][7] * b.w
                  + er[rr][8] * c.x + er[rr][9] * c.y + er[rr][10] * c.z + er[rr][11] * c.w
                  + er[rr][12] * d.x + er[rr][13] * d.y + er[rr][14] * d.z + er[rr][15] * d.w;
        const float r = fmaxf(dot, 0.0f);
        v[i][rr] = r;
        mx[rr] = fmaxf(mx[rr], r);
      }
    }
    const int wave = t >> 6, lane = t & 63;
#pragma unroll
    for (int rr = 0; rr < 4; ++rr) {
#pragma unroll
      for (int off = 32; off > 0; off >>= 1) mx[rr] = fmaxf(mx[rr], __shfl_xor(mx[rr], off, 64));
      if (lane == 0) redm[wave * 4 + rr] = mx[rr];
    }
    __syncthreads();
#pragma unroll
    for (int rr = 0; rr < 4; ++rr)
      mx[rr] = fmaxf(fmaxf(redm[rr], redm[4 + rr]), fmaxf(redm[8 + rr], redm[12 + rr]));
    float s[4] = {0.f, 0.f, 0.f, 0.f};
#pragma unroll
    for (int i = 0; i < 8; ++i)
#pragma unroll
      for (int rr = 0; rr < 4; ++rr) { v[i][rr] = __expf(v[i][rr] - mx[rr]); s[rr] += v[i][rr]; }
#pragma unroll
    for (int rr = 0; rr < 4; ++rr) {
#pragma unroll
      for (int off = 32; off > 0; off >>= 1) s[rr] += __shfl_xor(s[rr], off, 64);
      if (lane == 0) reds[wave * 4 + rr] = s[rr];
    }
    __syncthreads();
    float inv[4];
#pragma unroll
    for (int rr = 0; rr < 4; ++rr)
      inv[rr] = 1.0f / (reds[rr] + reds[4 + rr] + reds[8 + rr] + reds[12 + rr]);
#pragma unroll
    for (int i = 0; i < 8; ++i)
#pragma unroll
      for (int rr = 0; rr < 4; ++rr)
        Abf[(size_t)(n0base + rr) * NN + t + i * 256] = f2bf(v[i][rr] * inv[rr]);
    if (t < 64) {
#pragma unroll
      for (int rr = 0; rr < 4; ++rr) {
        float bs = 0.0f;
#pragma unroll
        for (int d = 0; d < 16; ++d) bs += esm[rr * 16 + d] * bp[d * 64 + t];
        Bias[(size_t)(n0base + rr) * 64 + t] = bs;
      }
    }
  } else {
    // ---- wp permute + W-fold: rq<8 -> wp0-wp2 ; rq>=16 -> 2*wp2 ----
    const int rq = id - 2560;
    for (int p = t; p < 1024; p += 256) {
      const int e0 = p * 8;
      const int d0 = e0 & 15;        // 0 or 8
      const int rem = e0 >> 4;       // o*8 + rl
      const int rl = rem & 7, o = rem >> 3;
      const int r = rq * 8 + rl;
      unsigned int w[4];
#pragma unroll
      for (int u = 0; u < 4; ++u) {
        float f0 = wp[(size_t)(d0 + 2 * u) * JJ + r * 64 + o];
        float f1 = wp[(size_t)(d0 + 2 * u + 1) * JJ + r * 64 + o];
        if (rq < 8) {        // W0' = W0 - W2  (W2 rows are r+128)
          f0 -= wp[(size_t)(d0 + 2 * u) * JJ + (r + 128) * 64 + o];
          f1 -= wp[(size_t)(d0 + 2 * u + 1) * JJ + (r + 128) * 64 + o];
        } else if (rq >= 16) {  // W2' = 2*W2
          f0 *= 2.0f;
          f1 *= 2.0f;
        }
        w[u] = f2bf(f0) | ((unsigned int)f2bf(f1) << 16);
      }
      *(uint4*)(wpT2 + (size_t)rq * 8192 + e0) = make_uint4(w[0], w[1], w[2], w[3]);
    }
  }
}

// ---------------------------------------------------------------------------
// Kernel 2: 128Mx64N BK=64 bf16 MFMA GEMM — the measured 55-59us structure:
// __launch_bounds__(256,4) / VGPR 48. ((256,6) caused scratch spill: R5/R7.)
// XOR swizzle phys = logical ^ ((row>>1)&7): 0 LDS conflicts (measured R3).
// Backfill: blocks id>=1024 run 768 make_w tiles per dispatch (mwbase 0/768).
// EPI=1: store G1 node-major + G1T. EPI=2: store H = A@G1 node-major only
// (F-subtraction folded into weights — see prep).
template <int EPI>
__global__ __launch_bounds__(256, 4) void gemm_mw(const unsigned short* __restrict__ A,
                                                  const unsigned short* __restrict__ Bt,
                                                  unsigned short* __restrict__ Cnm,
                                                  unsigned short* __restrict__ Ct,
                                                  const unsigned short* __restrict__ Ebf,
                                                  const unsigned short* __restrict__ wpT2,
                                                  unsigned short* __restrict__ Wg,
                                                  int mwbase) {
  __shared__ alignas(16) unsigned short As[128 * 64];  // 16KB
  __shared__ alignas(16) unsigned short Bs[64 * 64];   // 8KB
  const int id = blockIdx.x;
  const int t = threadIdx.x;
  const int wave = t >> 6, lane = t & 63;
  const int li = lane & 15, q = lane >> 4;

  if (id >= 1024) {
    // ---- make_w: Wg[n][j] = sum_d Ebf[n][d] * wpT2[j][d], K=32 (hi 16 zero) ----
    const int wid = id - 1024 + mwbase;   // [0,1536) across both dispatches
    const int bj = (wid % 96) * 128;
    const int bm = (wid / 96) * 128;
    gll16(Ebf  + (size_t)(bm + (t >> 1)) * 16 + (t & 1) * 8, &As[t * 8]);
    gll16(wpT2 + (size_t)(bj + (t >> 1)) * 16 + (t & 1) * 8, &Bs[t * 8]);
    __syncthreads();
    const int wm = (wave >> 1) * 64, wj = (wave & 1) * 64;
    const bool hiK = (q >= 2);
    const int qq = q & 1;
    bf16x8 vz;
#pragma unroll
    for (int i = 0; i < 8; ++i) vz[i] = (__bf16)0.0f;
    bf16x8 af[4], bfr[4];
#pragma unroll
    for (int r = 0; r < 4; ++r) {
      af[r] = *(const bf16x8*)&As[(wm + r * 16 + li) * 16 + qq * 8];
      if (hiK) af[r] = vz;
    }
#pragma unroll
    for (int c = 0; c < 4; ++c) {
      bfr[c] = *(const bf16x8*)&Bs[(wj + c * 16 + li) * 16 + qq * 8];
      if (hiK) bfr[c] = vz;
    }
    const int rowL = q * 4;
#pragma unroll
    for (int r = 0; r < 4; ++r) {
#pragma unroll
      for (int c = 0; c < 4; ++c) {
        f32x4 acc = (f32x4){0.f, 0.f, 0.f, 0.f};
        acc = __builtin_amdgcn_mfma_f32_16x16x32_bf16(af[r], bfr[c], acc, 0, 0, 0);
        const int gm = bm + wm + r * 16 + rowL;
        const int gj = bj + wj + c * 16 + li;
#pragma unroll
        for (int i = 0; i < 4; ++i)
          Wg[(size_t)(gm + i) * JJ + gj] = f2bf(acc[i]);
      }
    }
    return;
  }

  // ---- GEMM: bm=(id>>6)*128, bn=(id&63)*64 (locality-agnostic mapping) ----
  const int bm = (id >> 6) * 128, bn = (id & 63) * 64;
  const int wm = wave * 32;  // wave covers 32 M-rows x 64 N-cols

  f32x4 acc[2][4];
#pragma unroll
  for (int r = 0; r < 2; ++r)
#pragma unroll
    for (int c = 0; c < 4; ++c) acc[r][c] = (f32x4){0.f, 0.f, 0.f, 0.f};

  // staging: A 1024 chunks (4/thread), B 512 chunks (2/thread), 16B each.
  // chunk c: row = c>>3, pos = c&7; phys pos holds logical pos ^ ((row>>1)&7).
  const int srow = t >> 3;
  const int csw = (((t & 7) ^ ((t >> 4) & 7)) * 8);        // swizzled col (elems)
  const unsigned short* Ap[4];
  const unsigned short* Bp[2];
#pragma unroll
  for (int i = 0; i < 4; ++i) Ap[i] = A + (size_t)(bm + srow + i * 32) * NN + csw;
#pragma unroll
  for (int i = 0; i < 2; ++i) Bp[i] = Bt + (size_t)(bn + srow + i * 32) * NN + csw;
  const int sw = (li >> 1) & 7;

  for (int k0 = 0; k0 < NN; k0 += 64) {
    __syncthreads();  // prior-iter LDS reads done before overwrite
#pragma unroll
    for (int i = 0; i < 4; ++i) gll16(Ap[i] + k0, &As[(t + i * 256) * 8]);
#pragma unroll
    for (int i = 0; i < 2; ++i) gll16(Bp[i] + k0, &Bs[(t + i * 256) * 8]);
    __syncthreads();  // compiler drains vmcnt before s_barrier
#pragma unroll
    for (int kk = 0; kk < 2; ++kk) {
      const int kc = ((kk * 4 + q) ^ sw) * 8;
      bf16x8 af[2], bfr[4];
#pragma unroll
      for (int r = 0; r < 2; ++r)
        af[r] = *(const bf16x8*)&As[(wm + r * 16 + li) * 64 + kc];
#pragma unroll
      for (int c = 0; c < 4; ++c)
        bfr[c] = *(const bf16x8*)&Bs[(c * 16 + li) * 64 + kc];
#pragma unroll
      for (int r = 0; r < 2; ++r)
#pragma unroll
        for (int c = 0; c < 4; ++c)
          acc[r][c] = __builtin_amdgcn_mfma_f32_16x16x32_bf16(af[r], bfr[c], acc[r][c], 0, 0, 0);
    }
  }

  const int rowL = q * 4;  // C/D: col=lane&15, row=quad*4+i
#pragma unroll
  for (int r = 0; r < 2; ++r) {
#pragma unroll
    for (int c = 0; c < 4; ++c) {
      const int gm = bm + wm + r * 16 + rowL;
      const int gn = bn + c * 16 + li;
      const f32x4 a = acc[r][c];
#pragma unroll
      for (int i = 0; i < 4; ++i)
        Cnm[(size_t)(gm + i) * BC + gn] = f2bf(a[i]);
      if (EPI == 1) {
        const unsigned int lo = f2bf(a[0]) | ((unsigned int)f2bf(a[1]) << 16);
        const unsigned int hi = f2bf(a[2]) | ((unsigned int)f2bf(a[3]) << 16);
        *(uint2*)(Ct + (size_t)gn * NN + gm) = make_uint2(lo, hi);  // gm%4==0 -> 8B aligned
      }
    }
  }
}

// ---------------------------------------------------------------------------
// Kernel 3: per-node GEMM out[b,n,o] = X_n[64,192] @ W_n[192,64] + bias[n,o],
// X = [F | G1 | H] with the W-fold making this equal the reference output.
// LDS-free, barrier-free. No min-waves bound: let the compiler hoist the 30
// b128 global loads (VGPR ~150, ~3 blocks/CU) instead of serializing them
// under a VGPR cap — theory: this kernel was load-latency-bound at (256,6).
__global__ __launch_bounds__(256) void final_gemm(const unsigned short* __restrict__ Fbf,
                                                  const unsigned short* __restrict__ G1,
                                                  const unsigned short* __restrict__ H,
                                                  const unsigned short* __restrict__ Wg,
                                                  const float* __restrict__ Bias,
                                                  float* __restrict__ out) {
  const int n = blockIdx.x, t = threadIdx.x;
  const int wave = t >> 6, lane = t & 63;
  const int li = lane & 15, q = lane >> 4;
  const unsigned short* xb[3] = {Fbf + (size_t)n * BC + (size_t)(wave * 16 + li) * 64,
                                 G1  + (size_t)n * BC + (size_t)(wave * 16 + li) * 64,
                                 H   + (size_t)n * BC + (size_t)(wave * 16 + li) * 64};
  const unsigned short* wb = Wg + (size_t)n * JJ + (size_t)q * 512 + li * 8;

  f32x4 acc[4];
#pragma unroll
  for (int c = 0; c < 4; ++c) acc[c] = (f32x4){0.f, 0.f, 0.f, 0.f};
#pragma unroll
  for (int kq = 0; kq < 6; ++kq) {
    const bf16x8 a = *(const bf16x8*)(xb[kq >> 1] + (kq & 1) * 32 + q * 8);
#pragma unroll
    for (int c = 0; c < 4; ++c) {
      const bf16x8 b = *(const bf16x8*)(wb + (size_t)kq * 2048 + c * 128);
      acc[c] = __builtin_amdgcn_mfma_f32_16x16x32_bf16(a, b, acc[c], 0, 0, 0);
    }
  }
  const int rbase = wave * 16 + q * 4;
#pragma unroll
  for (int c = 0; c < 4; ++c) {
    const int o = c * 16 + li;
    const float bs = Bias[n * 64 + o];
#pragma unroll
    for (int i = 0; i < 4; ++i)
      out[(size_t)(rbase + i) * (NN * OO) + (size_t)n * OO + o] = acc[c][i] + bs;
  }
}

// ---------------------------------------------------------------------------
extern "C" void kernel_launch(void* const* d_in, const int* in_sizes, int n_in,
                              void* d_out, int out_size, void* d_ws, size_t ws_size,
                              hipStream_t stream) {
  const float* E    = (const float*)d_in[0];  // [2048,16]
  const float* feat = (const float*)d_in[1];  // [64,2048,64]
  const float* wp   = (const float*)d_in[2];  // [16,3,64,64]
  const float* bp   = (const float*)d_in[3];  // [16,64]
  float* out = (float*)d_out;

  char* ws = (char*)d_ws;
  size_t off = 0;
  auto alloc = [&](size_t bytes) -> void* {
    void* p = ws + off;
    off += (bytes + 255) & ~(size_t)255;
    return p;
  };
  unsigned short* Abf  = (unsigned short*)alloc((size_t)NN * NN * 2);   //  8 MB
  unsigned short* FbfT = (unsigned short*)alloc((size_t)BC * NN * 2);   // 16 MB (reused as H)
  unsigned short* Fbf  = (unsigned short*)alloc((size_t)NN * BC * 2);   // 16 MB
  unsigned short* G1   = (unsigned short*)alloc((size_t)NN * BC * 2);   // 16 MB
  unsigned short* G1T  = (unsigned short*)alloc((size_t)BC * NN * 2);   // 16 MB
  unsigned short* Wg   = (unsigned short*)alloc((size_t)NN * JJ * 2);   // 48 MB
  float* Bias          = (float*)alloc((size_t)NN * OO * 4);            // 0.5 MB
  unsigned short* Ebf  = (unsigned short*)alloc((size_t)NN * DE * 2);   // 64 KB
  unsigned short* wpT2 = (unsigned short*)alloc((size_t)JJ * DE * 2);   // 384 KB
  unsigned short* H    = FbfT;  // FbfT dead after GEMM1; GEMM2 reads G1T/Abf only

  prep<<<dim3(2584), 256, 0, stream>>>(feat, E, wp, bp, Fbf, FbfT, Abf, Bias, Ebf, wpT2);
  gemm_mw<1><<<dim3(1792), 256, 0, stream>>>(Abf, FbfT, G1, G1T, Ebf, wpT2, Wg, 0);
  gemm_mw<2><<<dim3(1792), 256, 0, stream>>>(Abf, G1T, H, nullptr, Ebf, wpT2, Wg, 768);
  final_gemm<<<dim3(2048), 256, 0, stream>>>(Fbf, G1, H, Wg, Bias, out);
}

// Round 10
// 216.950 us; speedup vs baseline: 1.0128x; 1.0128x over previous
//
#include <hip/hip_runtime.h>
#include <stdint.h>

// Problem constants (fixed by the reference)
#define NN 2048      // nodes
#define DE 16        // embedding dim
#define BB 64        // batch
#define CC 64        // in channels
#define OO 64        // out channels
#define BC 4096      // BB*CC
#define KR 192       // K*CC = 3*64 reduction length
#define JJ 12288     // KR*OO

using bf16x8 = __attribute__((ext_vector_type(8))) __bf16;
using f32x4  = __attribute__((ext_vector_type(4))) float;

__device__ __forceinline__ unsigned short f2bf(float f) {
  union { float f; unsigned int u; } v; v.f = f;
  unsigned int u = v.u;
  return (unsigned short)((u + 0x7FFFu + ((u >> 16) & 1u)) >> 16);  // RNE
}
// async global->LDS, 16B per lane. LDS dst is wave-uniform base + lane*16.
__device__ __forceinline__ void gll16(const void* g, void* l) {
  __builtin_amdgcn_global_load_lds(
      (const __attribute__((address_space(1))) unsigned int*)g,
      (__attribute__((address_space(3))) unsigned int*)l, 16, 0, 0);
}

// ---------------------------------------------------------------------------
// Kernel 1 ("prep"):
//   blocks [0,2048):    pack feat [B,N,C] fp32 -> Fbf [N][B*C] bf16 + FbfT [B*C][N]
//   blocks [2048,2560): adjacency softmax(relu(E E^T)), 4 rows per block; Bias; Ebf
//   blocks [2560,2584): permute wp fp32 -> wpT2[j][16] bf16, j = rq*512+o*8+rl,
//     with the ALGEBRAIC FOLD  W0' = W0 - W2,  W2' = 2*W2  so that downstream
//     out = F*W0' + G1*W1 + H*W2'  (H = A@G1) == reference F*W0+G1*W1+G2*W2.
__global__ __launch_bounds__(256) void prep(const float* __restrict__ feat,
                                            const float* __restrict__ E,
                                            const float* __restrict__ wp,
                                            const float* __restrict__ bp,
                                            unsigned short* __restrict__ Fbf,
                                            unsigned short* __restrict__ FbfT,
                                            unsigned short* __restrict__ Abf,
                                            float* __restrict__ Bias,
                                            unsigned short* __restrict__ Ebf,
                                            unsigned short* __restrict__ wpT2) {
  __shared__ float smem[64 * 65];  // 16.6 KB, reused per branch
  const int id = blockIdx.x;
  const int t  = threadIdx.x;

  if (id < 2048) {
    // ---- pack_feat: b = id>>5, n-tile = (id&31)*64 ----
    float (*tile)[65] = (float (*)[65])smem;  // +1 pad: conflict-free column reads
    const int b  = id >> 5;
    const int n0 = (id & 31) * 64;
    const int tr = t >> 4, tc4 = (t & 15) * 4;
#pragma unroll
    for (int i = 0; i < 4; ++i) {
      const int r = tr + i * 16;
      const float4 v = *(const float4*)(feat + (size_t)b * (NN * CC) + (size_t)(n0 + r) * CC + tc4);
      tile[r][tc4 + 0] = v.x; tile[r][tc4 + 1] = v.y;
      tile[r][tc4 + 2] = v.z; tile[r][tc4 + 3] = v.w;
    }
    __syncthreads();
#pragma unroll
    for (int i = 0; i < 4; ++i) {
      const int r = tr + i * 16;
      const unsigned int lo = f2bf(tile[r][tc4 + 0]) | ((unsigned int)f2bf(tile[r][tc4 + 1]) << 16);
      const unsigned int hi = f2bf(tile[r][tc4 + 2]) | ((unsigned int)f2bf(tile[r][tc4 + 3]) << 16);
      *(uint2*)(Fbf + (size_t)(n0 + r) * BC + b * CC + tc4) = make_uint2(lo, hi);
    }
    // transposed store, 8B per lane (4 consecutive n)
#pragma unroll
    for (int u = 0; u < 4; ++u) {
      const int p = t + u * 256;
      const int c = p >> 4, n4 = (p & 15) * 4;
      const unsigned int lo = f2bf(tile[n4 + 0][c]) | ((unsigned int)f2bf(tile[n4 + 1][c]) << 16);
      const unsigned int hi = f2bf(tile[n4 + 2][c]) | ((unsigned int)f2bf(tile[n4 + 3][c]) << 16);
      *(uint2*)(FbfT + (size_t)(b * CC + c) * NN + n0 + n4) = make_uint2(lo, hi);
    }
  } else if (id < 2560) {
    // ---- adj_softmax, 4 rows per block (correctness verified R6-R9) ----
    const int n0base = (id - 2048) * 4;
    float* esm  = smem;        // [64]
    float* redm = smem + 64;   // [16]
    float* reds = smem + 80;   // [16]
    if (t < 64) esm[t] = E[n0base * 16 + t];
    __syncthreads();
    if (t < 64) Ebf[n0base * 16 + t] = f2bf(esm[t]);
    float er[4][16];
#pragma unroll
    for (int rr = 0; rr < 4; ++rr)
#pragma unroll
      for (int d = 0; d < 16; ++d) er[rr][d] = esm[rr * 16 + d];

    float v[8][4];
    float mx[4] = {0.f, 0.f, 0.f, 0.f};  // relu floor
#pragma unroll
    for (int i = 0; i < 8; ++i) {
      const int m = t + i * 256;
      const float4* Em = (const float4*)(E + m * 16);
      const float4 a = Em[0], b = Em[1], c = Em[2], d = Em[3];
#pragma unroll
      for (int rr = 0; rr < 4; ++rr) {
        float dot = er[rr][0] * a.x + er[rr][1] * a.y + er[rr][2] * a.z + er[rr][3] * a.w
                  + er[rr][4] * b.x + er[rr][5] * b.y + er[rr][6] * b.z + er[rr][7] * b.w
                  + er[rr][8] * c.x + er[rr][9] * c.y + er[rr][10] * c.z + er[rr][11] * c.w
                  + er[rr][12] * d.x + er[rr][13] * d.y + er[rr][14] * d.z + er[rr][15] * d.w;
        const float r = fmaxf(dot, 0.0f);
        v[i][rr] = r;
        mx[rr] = fmaxf(mx[rr], r);
      }
    }
    const int wave = t >> 6, lane = t & 63;
#pragma unroll
    for (int rr = 0; rr < 4; ++rr) {
#pragma unroll
      for (int off = 32; off > 0; off >>= 1) mx[rr] = fmaxf(mx[rr], __shfl_xor(mx[rr], off, 64));
      if (lane == 0) redm[wave * 4 + rr] = mx[rr];
    }
    __syncthreads();
#pragma unroll
    for (int rr = 0; rr < 4; ++rr)
      mx[rr] = fmaxf(fmaxf(redm[rr], redm[4 + rr]), fmaxf(redm[8 + rr], redm[12 + rr]));
    float s[4] = {0.f, 0.f, 0.f, 0.f};
#pragma unroll
    for (int i = 0; i < 8; ++i)
#pragma unroll
      for (int rr = 0; rr < 4; ++rr) { v[i][rr] = __expf(v[i][rr] - mx[rr]); s[rr] += v[i][rr]; }
#pragma unroll
    for (int rr = 0; rr < 4; ++rr) {
#pragma unroll
      for (int off = 32; off > 0; off >>= 1) s[rr] += __shfl_xor(s[rr], off, 64);
      if (lane == 0) reds[wave * 4 + rr] = s[rr];
    }
    __syncthreads();
    float inv[4];
#pragma unroll
    for (int rr = 0; rr < 4; ++rr)
      inv[rr] = 1.0f / (reds[rr] + reds[4 + rr] + reds[8 + rr] + reds[12 + rr]);
#pragma unroll
    for (int i = 0; i < 8; ++i)
#pragma unroll
      for (int rr = 0; rr < 4; ++rr)
        Abf[(size_t)(n0base + rr) * NN + t + i * 256] = f2bf(v[i][rr] * inv[rr]);
    if (t < 64) {
#pragma unroll
      for (int rr = 0; rr < 4; ++rr) {
        float bs = 0.0f;
#pragma unroll
        for (int d = 0; d < 16; ++d) bs += esm[rr * 16 + d] * bp[d * 64 + t];
        Bias[(size_t)(n0base + rr) * 64 + t] = bs;
      }
    }
  } else {
    // ---- wp permute + W-fold: rq<8 -> wp0-wp2 ; rq>=16 -> 2*wp2 ----
    const int rq = id - 2560;
    for (int p = t; p < 1024; p += 256) {
      const int e0 = p * 8;
      const int d0 = e0 & 15;        // 0 or 8
      const int rem = e0 >> 4;       // o*8 + rl
      const int rl = rem & 7, o = rem >> 3;
      const int r = rq * 8 + rl;
      unsigned int w[4];
#pragma unroll
      for (int u = 0; u < 4; ++u) {
        float f0 = wp[(size_t)(d0 + 2 * u) * JJ + r * 64 + o];
        float f1 = wp[(size_t)(d0 + 2 * u + 1) * JJ + r * 64 + o];
        if (rq < 8) {        // W0' = W0 - W2  (W2 rows are r+128)
          f0 -= wp[(size_t)(d0 + 2 * u) * JJ + (r + 128) * 64 + o];
          f1 -= wp[(size_t)(d0 + 2 * u + 1) * JJ + (r + 128) * 64 + o];
        } else if (rq >= 16) {  // W2' = 2*W2
          f0 *= 2.0f;
          f1 *= 2.0f;
        }
        w[u] = f2bf(f0) | ((unsigned int)f2bf(f1) << 16);
      }
      *(uint4*)(wpT2 + (size_t)rq * 8192 + e0) = make_uint4(w[0], w[1], w[2], w[3]);
    }
  }
}

// ---------------------------------------------------------------------------
// Kernel 2: 128Mx64N BK=64 bf16 MFMA GEMM — the measured 52.5us structure:
// __launch_bounds__(256,4) / VGPR 48. ((256,6) caused scratch spill: R5/R7.)
// XOR swizzle phys = logical ^ ((row>>1)&7): 0 LDS conflicts (measured R3).
// Backfill: blocks id>=1024 run 768 make_w tiles per dispatch (mwbase 0/768).
// EPI=1: store G1 node-major + G1T. EPI=2: store H = A@G1 node-major only
// (F-subtraction folded into weights — see prep).
template <int EPI>
__global__ __launch_bounds__(256, 4) void gemm_mw(const unsigned short* __restrict__ A,
                                                  const unsigned short* __restrict__ Bt,
                                                  unsigned short* __restrict__ Cnm,
                                                  unsigned short* __restrict__ Ct,
                                                  const unsigned short* __restrict__ Ebf,
                                                  const unsigned short* __restrict__ wpT2,
                                                  unsigned short* __restrict__ Wg,
                                                  int mwbase) {
  __shared__ alignas(16) unsigned short As[128 * 64];  // 16KB
  __shared__ alignas(16) unsigned short Bs[64 * 64];   // 8KB
  const int id = blockIdx.x;
  const int t = threadIdx.x;
  const int wave = t >> 6, lane = t & 63;
  const int li = lane & 15, q = lane >> 4;

  if (id >= 1024) {
    // ---- make_w: Wg[n][j] = sum_d Ebf[n][d] * wpT2[j][d], K=32 (hi 16 zero) ----
    const int wid = id - 1024 + mwbase;   // [0,1536) across both dispatches
    const int bj = (wid % 96) * 128;
    const int bm = (wid / 96) * 128;
    gll16(Ebf  + (size_t)(bm + (t >> 1)) * 16 + (t & 1) * 8, &As[t * 8]);
    gll16(wpT2 + (size_t)(bj + (t >> 1)) * 16 + (t & 1) * 8, &Bs[t * 8]);
    __syncthreads();
    const int wm = (wave >> 1) * 64, wj = (wave & 1) * 64;
    const bool hiK = (q >= 2);
    const int qq = q & 1;
    bf16x8 vz;
#pragma unroll
    for (int i = 0; i < 8; ++i) vz[i] = (__bf16)0.0f;
    bf16x8 af[4], bfr[4];
#pragma unroll
    for (int r = 0; r < 4; ++r) {
      af[r] = *(const bf16x8*)&As[(wm + r * 16 + li) * 16 + qq * 8];
      if (hiK) af[r] = vz;
    }
#pragma unroll
    for (int c = 0; c < 4; ++c) {
      bfr[c] = *(const bf16x8*)&Bs[(wj + c * 16 + li) * 16 + qq * 8];
      if (hiK) bfr[c] = vz;
    }
    const int rowL = q * 4;
#pragma unroll
    for (int r = 0; r < 4; ++r) {
#pragma unroll
      for (int c = 0; c < 4; ++c) {
        f32x4 acc = (f32x4){0.f, 0.f, 0.f, 0.f};
        acc = __builtin_amdgcn_mfma_f32_16x16x32_bf16(af[r], bfr[c], acc, 0, 0, 0);
        const int gm = bm + wm + r * 16 + rowL;
        const int gj = bj + wj + c * 16 + li;
#pragma unroll
        for (int i = 0; i < 4; ++i)
          Wg[(size_t)(gm + i) * JJ + gj] = f2bf(acc[i]);
      }
    }
    return;
  }

  // ---- GEMM: bm=(id>>6)*128, bn=(id&63)*64 (locality-agnostic mapping) ----
  const int bm = (id >> 6) * 128, bn = (id & 63) * 64;
  const int wm = wave * 32;  // wave covers 32 M-rows x 64 N-cols

  f32x4 acc[2][4];
#pragma unroll
  for (int r = 0; r < 2; ++r)
#pragma unroll
    for (int c = 0; c < 4; ++c) acc[r][c] = (f32x4){0.f, 0.f, 0.f, 0.f};

  // staging: A 1024 chunks (4/thread), B 512 chunks (2/thread), 16B each.
  // chunk c: row = c>>3, pos = c&7; phys pos holds logical pos ^ ((row>>1)&7).
  const int srow = t >> 3;
  const int csw = (((t & 7) ^ ((t >> 4) & 7)) * 8);        // swizzled col (elems)
  const unsigned short* Ap[4];
  const unsigned short* Bp[2];
#pragma unroll
  for (int i = 0; i < 4; ++i) Ap[i] = A + (size_t)(bm + srow + i * 32) * NN + csw;
#pragma unroll
  for (int i = 0; i < 2; ++i) Bp[i] = Bt + (size_t)(bn + srow + i * 32) * NN + csw;
  const int sw = (li >> 1) & 7;

  for (int k0 = 0; k0 < NN; k0 += 64) {
    __syncthreads();  // prior-iter LDS reads done before overwrite
#pragma unroll
    for (int i = 0; i < 4; ++i) gll16(Ap[i] + k0, &As[(t + i * 256) * 8]);
#pragma unroll
    for (int i = 0; i < 2; ++i) gll16(Bp[i] + k0, &Bs[(t + i * 256) * 8]);
    __syncthreads();  // compiler drains vmcnt before s_barrier
#pragma unroll
    for (int kk = 0; kk < 2; ++kk) {
      const int kc = ((kk * 4 + q) ^ sw) * 8;
      bf16x8 af[2], bfr[4];
#pragma unroll
      for (int r = 0; r < 2; ++r)
        af[r] = *(const bf16x8*)&As[(wm + r * 16 + li) * 64 + kc];
#pragma unroll
      for (int c = 0; c < 4; ++c)
        bfr[c] = *(const bf16x8*)&Bs[(c * 16 + li) * 64 + kc];
#pragma unroll
      for (int r = 0; r < 2; ++r)
#pragma unroll
        for (int c = 0; c < 4; ++c)
          acc[r][c] = __builtin_amdgcn_mfma_f32_16x16x32_bf16(af[r], bfr[c], acc[r][c], 0, 0, 0);
    }
  }

  const int rowL = q * 4;  // C/D: col=lane&15, row=quad*4+i
#pragma unroll
  for (int r = 0; r < 2; ++r) {
#pragma unroll
    for (int c = 0; c < 4; ++c) {
      const int gm = bm + wm + r * 16 + rowL;
      const int gn = bn + c * 16 + li;
      const f32x4 a = acc[r][c];
#pragma unroll
      for (int i = 0; i < 4; ++i)
        Cnm[(size_t)(gm + i) * BC + gn] = f2bf(a[i]);
      if (EPI == 1) {
        const unsigned int lo = f2bf(a[0]) | ((unsigned int)f2bf(a[1]) << 16);
        const unsigned int hi = f2bf(a[2]) | ((unsigned int)f2bf(a[3]) << 16);
        *(uint2*)(Ct + (size_t)gn * NN + gm) = make_uint2(lo, hi);  // gm%4==0 -> 8B aligned
      }
    }
  }
}

// ---------------------------------------------------------------------------
// Kernel 3: per-node GEMM out[b,n,o] = X_n[64,192] @ W_n[192,64] + bias[n,o],
// X = [F | G1 | H] with the W-fold making this equal the reference output.
// LDS-free, barrier-free. __launch_bounds__(256,6): the R8-measured config —
// removing it (R9) cost ~19us (VGPR growth halved blocks/CU; this kernel
// relies on cross-block TLP to cover its serialized b128 load latencies).
// Nontemporal out stores: 32MB fp32 never re-read — don't evict L2.
__global__ __launch_bounds__(256, 6) void final_gemm(const unsigned short* __restrict__ Fbf,
                                                     const unsigned short* __restrict__ G1,
                                                     const unsigned short* __restrict__ H,
                                                     const unsigned short* __restrict__ Wg,
                                                     const float* __restrict__ Bias,
                                                     float* __restrict__ out) {
  const int n = blockIdx.x, t = threadIdx.x;
  const int wave = t >> 6, lane = t & 63;
  const int li = lane & 15, q = lane >> 4;
  const unsigned short* xb[3] = {Fbf + (size_t)n * BC + (size_t)(wave * 16 + li) * 64,
                                 G1  + (size_t)n * BC + (size_t)(wave * 16 + li) * 64,
                                 H   + (size_t)n * BC + (size_t)(wave * 16 + li) * 64};
  const unsigned short* wb = Wg + (size_t)n * JJ + (size_t)q * 512 + li * 8;

  f32x4 acc[4];
#pragma unroll
  for (int c = 0; c < 4; ++c) acc[c] = (f32x4){0.f, 0.f, 0.f, 0.f};
#pragma unroll
  for (int kq = 0; kq < 6; ++kq) {
    const bf16x8 a = *(const bf16x8*)(xb[kq >> 1] + (kq & 1) * 32 + q * 8);
#pragma unroll
    for (int c = 0; c < 4; ++c) {
      const bf16x8 b = *(const bf16x8*)(wb + (size_t)kq * 2048 + c * 128);
      acc[c] = __builtin_amdgcn_mfma_f32_16x16x32_bf16(a, b, acc[c], 0, 0, 0);
    }
  }
  const int rbase = wave * 16 + q * 4;
#pragma unroll
  for (int c = 0; c < 4; ++c) {
    const int o = c * 16 + li;
    const float bs = Bias[n * 64 + o];
#pragma unroll
    for (int i = 0; i < 4; ++i)
      __builtin_nontemporal_store(acc[c][i] + bs,
          out + (size_t)(rbase + i) * (NN * OO) + (size_t)n * OO + o);
  }
}

// ---------------------------------------------------------------------------
extern "C" void kernel_launch(void* const* d_in, const int* in_sizes, int n_in,
                              void* d_out, int out_size, void* d_ws, size_t ws_size,
                              hipStream_t stream) {
  const float* E    = (const float*)d_in[0];  // [2048,16]
  const float* feat = (const float*)d_in[1];  // [64,2048,64]
  const float* wp   = (const float*)d_in[2];  // [16,3,64,64]
  const float* bp   = (const float*)d_in[3];  // [16,64]
  float* out = (float*)d_out;

  char* ws = (char*)d_ws;
  size_t off = 0;
  auto alloc = [&](size_t bytes) -> void* {
    void* p = ws + off;
    off += (bytes + 255) & ~(size_t)255;
    return p;
  };
  unsigned short* Abf  = (unsigned short*)alloc((size_t)NN * NN * 2);   //  8 MB
  unsigned short* FbfT = (unsigned short*)alloc((size_t)BC * NN * 2);   // 16 MB (reused as H)
  unsigned short* Fbf  = (unsigned short*)alloc((size_t)NN * BC * 2);   // 16 MB
  unsigned short* G1   = (unsigned short*)alloc((size_t)NN * BC * 2);   // 16 MB
  unsigned short* G1T  = (unsigned short*)alloc((size_t)BC * NN * 2);   // 16 MB
  unsigned short* Wg   = (unsigned short*)alloc((size_t)NN * JJ * 2);   // 48 MB
  float* Bias          = (float*)alloc((size_t)NN * OO * 4);            // 0.5 MB
  unsigned short* Ebf  = (unsigned short*)alloc((size_t)NN * DE * 2);   // 64 KB
  unsigned short* wpT2 = (unsigned short*)alloc((size_t)JJ * DE * 2);   // 384 KB
  unsigned short* H    = FbfT;  // FbfT dead after GEMM1; GEMM2 reads G1T/Abf only

  prep<<<dim3(2584), 256, 0, stream>>>(feat, E, wp, bp, Fbf, FbfT, Abf, Bias, Ebf, wpT2);
  gemm_mw<1><<<dim3(1792), 256, 0, stream>>>(Abf, FbfT, G1, G1T, Ebf, wpT2, Wg, 0);
  gemm_mw<2><<<dim3(1792), 256, 0, stream>>>(Abf, G1T, H, nullptr, Ebf, wpT2, Wg, 768);
  final_gemm<<<dim3(2048), 256, 0, stream>>>(Fbf, G1, H, Wg, Bias, out);
}